// Round 9
// baseline (540.492 us; speedup 1.0000x reference)
//
#include <hip/hip_runtime.h>
#include <cfloat>

// ---- problem dims ----
#define NN    16380
#define RR    819
#define APR   20
#define KNB   16
#define HID   64
#define LAYERS 6
#define BINS  100
#define N64   (NN*HID)

// ---- geometry ----
#define ATB   32
#define NBLK  512               // 512*32 = 16384 >= NN
#define LDA   68
#define LDU   132
#define CSIZE 4.375f            // 70/16

// ---- workspace float offsets ----
#define OFF_QA    0
#define OFF_KA    (1*N64)
#define OFF_FA    (2*N64)
#define OFF_QB    (3*N64)
#define OFF_KB    (4*N64)
#define OFF_FB    (5*N64)
#define OFF_VA    (6*N64)           // 3 planes
#define OFF_VB    (9*N64)           // 3 planes
#define OFF_S     (12*N64)
#define OFF_DIRNS (13*N64)          // N*48 (sorted space)
#define OFF_C4    (OFF_DIRNS + NN*48)
#define OFF_C4S   (OFF_C4 + NN*4)
#define OFF_RES   (OFF_C4S + NN*4)
#define OFF_NBRS  (OFF_RES + RR*64)    // int N*16 (sorted space)
#define OFF_BINSS (OFF_NBRS + NN*16)   // int N*16
#define OFF_O2N   (OFF_BINSS + NN*16)  // int N
#define OFF_N2O   (OFF_O2N + NN)       // int N
#define OFF_CELL  (OFF_N2O + NN)       // int N
#define OFF_HIST  (OFF_CELL + NN)      // int 4096
#define OFF_CNT   (OFF_HIST + 4096)    // int 4096 (adjacent: one memset covers both)
#define OFF_BASE  (OFF_CNT + 4096)     // int 4096

typedef unsigned long long u64;
#define U64MAX 0xFFFFFFFFFFFFFFFFull

typedef float f32x2 __attribute__((ext_vector_type(2)));

// Round-8: fast transcendentals (kept; -43us). Round-9: GEMM inner loops moved
// to v_pk_fma_f32 via <2 x float> __builtin_elementwise_fma -- the empirical
// lesson from round-8 is that VALU instruction count is ~3x amplified into wall
// time at 2 waves/SIMD, and the 11x512 scalar GEMM FMAs are the largest block.
__device__ __forceinline__ float gelu_f(float x) {
    float x3 = x*x*x;
    float z = 0.7978845608028654f*(x + 0.044715f*x3);
    float t = 1.0f - 2.0f/(__expf(2.0f*z) + 1.0f);   // tanh(z)
    return 0.5f*x*(1.0f+t);
}
__device__ __forceinline__ float sigmoid_f(float x) {
    return 1.0f/(1.0f + __expf(-x));
}
__device__ __forceinline__ int spread3(int x) {   // 4-bit -> every 3rd bit
    return (x&1) | ((x&2)<<2) | ((x&4)<<4) | ((x&8)<<6);
}
__device__ __forceinline__ unsigned sortable_u32(float f) {
    unsigned u = __float_as_uint(f);
    return u ^ ((u & 0x80000000u) ? 0xFFFFFFFFu : 0x80000000u);
}

// ---------------- fused pad + cell-id + histogram + resb zero ----------------
__global__ void pad_cell_kernel(const float* __restrict__ coords, float4* __restrict__ c4,
                                int* __restrict__ cellid, int* __restrict__ hist,
                                float* __restrict__ resb, int n) {
    int i = blockIdx.x*256 + threadIdx.x;
    for (int j = i; j < RR*HID; j += 16384) resb[j] = 0.f;
    if (i >= n) return;
    float x = coords[3*i], y = coords[3*i+1], z = coords[3*i+2];
    float sq = __fadd_rn(__fadd_rn(__fmul_rn(x,x), __fmul_rn(y,y)), __fmul_rn(z,z));
    c4[i] = make_float4(x, y, z, sq);
    int cx = min(15, max(0, (int)(x * (16.0f/70.0f))));
    int cy = min(15, max(0, (int)(y * (16.0f/70.0f))));
    int cz = min(15, max(0, (int)(z * (16.0f/70.0f))));
    int m = spread3(cx) | (spread3(cy)<<1) | (spread3(cz)<<2);
    cellid[i] = m;
    atomicAdd(&hist[m], 1);
}
__global__ void scan_kernel(const int* __restrict__ hist, int* __restrict__ base) {
    __shared__ int part[256];
    int t = threadIdx.x;
    int loc[16]; int s = 0;
    #pragma unroll
    for (int e = 0; e < 16; ++e) { loc[e] = s; s += hist[t*16+e]; }
    part[t] = s;
    __syncthreads();
    if (t == 0) { int acc = 0; for (int i = 0; i < 256; ++i) { int v = part[i]; part[i] = acc; acc += v; } }
    __syncthreads();
    int off = part[t];
    #pragma unroll
    for (int e = 0; e < 16; ++e) base[t*16+e] = off + loc[e];
}
__global__ void scatter_kernel(const int* __restrict__ cellid, const int* __restrict__ base,
                               int* __restrict__ cnt, int* __restrict__ o2n,
                               int* __restrict__ n2o, const float4* __restrict__ c4,
                               float4* __restrict__ c4s, int n) {
    int i = blockIdx.x*256 + threadIdx.x;
    if (i >= n) return;
    int m = cellid[i];
    int pos = base[m] + atomicAdd(&cnt[m], 1);
    o2n[i] = pos; n2o[pos] = i;
    c4s[pos] = c4[i];
}

// ---------------- grid kNN: bitonic + pre-sort chunk rejection ----------------
#define SCRATCH 1024
__global__ __launch_bounds__(256) void knn_grid_kernel(
    const float4* __restrict__ c4s, const int* __restrict__ base, const int* __restrict__ hist,
    const int* __restrict__ n2o, const int* __restrict__ o2n,
    int* __restrict__ nbr, int* __restrict__ binsO, float* __restrict__ dirn, int n)
{
    __shared__ int sIdx[4][SCRATCH];
    int tid = threadIdx.x;
    int wv = tid >> 6, lane = tid & 63;
    int i = blockIdx.x*4 + wv;
    bool valid = i < n;
    int ii = valid ? i : 0;
    float4 cd = c4s[ii];
    float sqd = cd.w;
    int cx = min(15, max(0, (int)(cd.x * (16.0f/70.0f))));
    int cy = min(15, max(0, (int)(cd.y * (16.0f/70.0f))));
    int cz = min(15, max(0, (int)(cd.z * (16.0f/70.0f))));
    u64 dlist = U64MAX;
    u64 vmax  = U64MAX;
    int* sidx = sIdx[wv];

    auto compute_pk = [&](int idx) -> u64 {
        if (idx == i) return U64MAX;
        float4 cc = c4s[idx];
        float dt = __fmul_rn(cd.x, cc.x);
        dt = __fmaf_rn(cd.y, cc.y, dt);
        dt = __fmaf_rn(cd.z, cc.z, dt);
        float key = __fsub_rn(__fadd_rn(sqd, cc.w), __fmul_rn(2.0f, dt));
        int org = n2o[idx];
        return ((u64)sortable_u32(key) << 32) | (unsigned)org;
    };

    auto process_batch = [&](int M) {
        if (M <= 0) return;
        for (int c0 = 0; c0 < M; c0 += 64) {
            int p = c0 + lane;
            u64 v = (p < M) ? compute_pk(sidx[p]) : U64MAX;
            // ---- pre-sort rejection: wave-min of chunk vs current 16th-best ----
            u64 mn = v;
            #pragma unroll
            for (int off = 1; off < 64; off <<= 1) {
                u64 o = __shfl_xor(mn, off);
                mn = (o < mn) ? o : mn;
            }
            if (mn >= vmax) continue;       // wave-uniform after butterfly
            // ---- bitonic sort: 64 keys ascending across lanes ----
            #pragma unroll
            for (int k = 2; k <= 64; k <<= 1) {
                #pragma unroll
                for (int j = k >> 1; j > 0; j >>= 1) {
                    u64 o = __shfl_xor(v, j);
                    bool keepmin = (((lane & j) == 0) == ((lane & k) == 0));
                    u64 mnn = (v < o) ? v : o;
                    u64 mxx = (v < o) ? o : v;
                    v = keepmin ? mnn : mxx;
                }
            }
            // ---- merge: [dlist asc lanes0-15 | chunk top16 desc lanes16-31] ----
            u64 bm = __shfl(v, (31 - lane) & 63);
            u64 m = (lane < 16) ? dlist : bm;
            #pragma unroll
            for (int j = 16; j > 0; j >>= 1) {
                u64 o = __shfl_xor(m, j);
                u64 mnn = (m < o) ? m : o;
                u64 mxx = (m < o) ? o : m;
                m = ((lane & j) == 0) ? mnn : mxx;
            }
            if (lane < 16) dlist = m;
            vmax = __shfl(dlist, 15);
        }
    };

    for (int R = 1; R <= 16; ++R) {
        int side = 2*R+1;
        int ncell = side*side*side;
        int M = 0;
        for (int t0 = 0; t0 < ncell; t0 += 64) {
            int t = t0 + lane;
            int cnt = 0, b = 0;
            if (t < ncell) {
                int dxc = t % side - R;
                int dyc = (t/side) % side - R;
                int dzc = t/(side*side) - R;
                int ch = max(abs(dxc), max(abs(dyc), abs(dzc)));
                bool use = (R == 1) || (ch == R);
                int x = cx+dxc, y = cy+dyc, z = cz+dzc;
                if (use && x>=0 && x<16 && y>=0 && y<16 && z>=0 && z<16) {
                    int m = spread3(x) | (spread3(y)<<1) | (spread3(z)<<2);
                    cnt = hist[m]; b = base[m];
                }
            }
            int incl = cnt;
            #pragma unroll
            for (int o = 1; o < 64; o <<= 1) { int v = __shfl_up(incl, o); if (lane >= o) incl += v; }
            int excl = incl - cnt;
            int tot = __shfl(incl, 63);
            if (M + tot > SCRATCH) { process_batch(M); M = 0; }
            for (int e = 0; e < cnt; ++e) {
                int pos = M + excl + e;
                if (pos < SCRATCH) sidx[pos] = b + e;
            }
            M = min(M + tot, SCRATCH);
        }
        process_batch(M);
        float rim = (float)R * CSIZE;
        unsigned thS = sortable_u32(rim*rim - 0.05f);
        if ((unsigned)(vmax >> 32) < thS) break;
    }
    if (valid && lane < 16) {
        int org = (int)(dlist & 0xFFFFFFFFull);
        int src = o2n[org];
        float4 cs = c4s[src];
        float dx = __fsub_rn(cd.x, cs.x);
        float dy = __fsub_rn(cd.y, cs.y);
        float dz = __fsub_rn(cd.z, cs.z);
        float ss = __fadd_rn(__fadd_rn(__fmul_rn(dx,dx), __fmul_rn(dy,dy)),
                             __fmul_rn(dz,dz));
        float dd = __fsqrt_rn(__fadd_rn(ss, 1e-12f));
        nbr[i*KNB + lane] = src;
        float bf = __fmul_rn(__fdiv_rn(dd, 10.0f), 100.0f);
        int b = (int)bf;
        b = min(max(b, 0), BINS-1);
        binsO[i*KNB + lane] = b;
        dirn[i*48 + lane*3 + 0] = __fdiv_rn(dx, dd);
        dirn[i*48 + lane*3 + 1] = __fdiv_rn(dy, dd);
        dirn[i*48 + lane*3 + 2] = __fdiv_rn(dz, dd);
    }
}

// ---------------- prologue (pk-FMA GEMM) ----------------
__global__ __launch_bounds__(256) void prologue_kernel(
    const int* __restrict__ aid, const int* __restrict__ rid, const int* __restrict__ eid,
    const int* __restrict__ n2o,
    const float* __restrict__ ea, const float* __restrict__ er, const float* __restrict__ ee,
    const float* __restrict__ Win, const float* __restrict__ Wq, const float* __restrict__ Wk,
    const float* __restrict__ Wv,
    float* __restrict__ sg, float* __restrict__ qout, float* __restrict__ kout,
    float* __restrict__ vfout)
{
    __shared__ __align__(16) float sS[ATB*LDA];
    __shared__ __align__(16) float sH[ATB*LDA];
    __shared__ __align__(16) float sW[4096];
    const int tid = threadIdx.x;
    const int a0 = blockIdx.x*ATB;
    const int gi = tid>>4, gj = tid&15;
    const int lrow = tid>>3, lsub = tid&7;

    auto stageW = [&](const float* W) {
        const float4* src = (const float4*)W; float4* dst = (float4*)sW;
        #pragma unroll
        for (int r = 0; r < 4; ++r) dst[tid + 256*r] = src[tid + 256*r];
    };
    auto do_gemm = [&](const float* sA, float4& C0, float4& C1) {
        const float* a0p = sA + gi*LDA;
        const float* a1p = sA + (gi+16)*LDA;
        const float* wr  = sW + gj*4;
        f32x2 c0l = {C0.x, C0.y}, c0h = {C0.z, C0.w};
        f32x2 c1l = {C1.x, C1.y}, c1h = {C1.z, C1.w};
        #pragma unroll 8
        for (int k = 0; k < 64; ++k) {
            float av0 = a0p[k], av1 = a1p[k];
            float4 w = *(const float4*)(wr + k*64);
            f32x2 wl = {w.x, w.y}, wh = {w.z, w.w};
            f32x2 va0 = {av0, av0}, va1 = {av1, av1};
            c0l = __builtin_elementwise_fma(va0, wl, c0l);
            c0h = __builtin_elementwise_fma(va0, wh, c0h);
            c1l = __builtin_elementwise_fma(va1, wl, c1l);
            c1h = __builtin_elementwise_fma(va1, wh, c1h);
        }
        C0 = make_float4(c0l.x, c0l.y, c0h.x, c0h.y);
        C1 = make_float4(c1l.x, c1l.y, c1h.x, c1h.y);
    };
    auto do_ln = [&](const float* src, float* dst) {
        const float* sp = src + lrow*LDA + lsub*8;
        float v[8]; float s1 = 0.f;
        #pragma unroll
        for (int e = 0; e < 8; ++e) { v[e] = sp[e]; s1 += v[e]; }
        s1 += __shfl_xor(s1,1); s1 += __shfl_xor(s1,2); s1 += __shfl_xor(s1,4);
        float mean = s1*(1.0f/64.0f);
        float s2 = 0.f;
        #pragma unroll
        for (int e = 0; e < 8; ++e) { float t = v[e]-mean; s2 += t*t; }
        s2 += __shfl_xor(s2,1); s2 += __shfl_xor(s2,2); s2 += __shfl_xor(s2,4);
        float sc = 1.0f/sqrtf(s2*(1.0f/64.0f)+1e-5f);
        float* dp = dst + lrow*LDA + lsub*8;
        #pragma unroll
        for (int e = 0; e < 8; ++e) dp[e] = (v[e]-mean)*sc;
    };
    auto store_g = [&](float* base, float4 c0, float4 c1) {
        int g0 = a0+gi, g1 = a0+gi+16;
        if (g0 < NN) *(float4*)(base + (size_t)g0*64 + gj*4) = c0;
        if (g1 < NN) *(float4*)(base + (size_t)g1*64 + gj*4) = c1;
    };

    {   // feat -> sH  (overlapped with Win staging; both guarded by next sync)
        int ga = a0 + lrow;
        int io = (ga < NN) ? n2o[ga] : 0;
        #pragma unroll
        for (int e = 0; e < 8; ++e) {
            int c = lsub*8 + e;
            float x = 0.f;
            if (ga < NN) {
                if (c < 32)      x = ea[aid[io]*32 + c];
                else if (c < 48) x = er[rid[io]*16 + (c-32)];
                else             x = ee[eid[io]*16 + (c-48)];
            }
            sH[lrow*LDA + c] = x;
        }
    }
    stageW(Win);
    __syncthreads();
    {
        float4 c0 = make_float4(0,0,0,0), c1 = c0;
        do_gemm(sH, c0, c1);
        *(float4*)(sS + gi*LDA + gj*4)      = c0;
        *(float4*)(sS + (gi+16)*LDA + gj*4) = c1;
        store_g(sg, c0, c1);
    }
    __syncthreads();                 // all done with sH(feat), sW(Win); sS written
    do_ln(sS, sH);                   // overlap LN with Wk staging
    stageW(Wk);
    __syncthreads();
    { float4 c0 = make_float4(0,0,0,0), c1 = c0; do_gemm(sH, c0, c1); store_g(kout, c0, c1); }
    __syncthreads();
    stageW(Wv); __syncthreads();
    { float4 c0 = make_float4(0,0,0,0), c1 = c0; do_gemm(sH, c0, c1); store_g(vfout, c0, c1); }
    __syncthreads();
    stageW(Wq); __syncthreads();
    { float4 c0 = make_float4(0,0,0,0), c1 = c0; do_gemm(sH, c0, c1); store_g(qout, c0, c1); }
}

// ---------------- fused layer kernel: round-6 schedule + fast-exp + pk-FMA ----------------
__global__ __launch_bounds__(256) void layer_kernel(
    const float* __restrict__ qin, const float* __restrict__ kin, const float* __restrict__ vfin,
    float* __restrict__ qout, float* __restrict__ kout, float* __restrict__ vfout,
    const float* __restrict__ vin, float* __restrict__ vout,
    float* __restrict__ sg, const float* __restrict__ dirn,
    const int* __restrict__ nbr, const int* __restrict__ bins,
    float* __restrict__ resb, const int* __restrict__ ridx, const int* __restrict__ n2o,
    const float* __restrict__ Wvec, const float* __restrict__ wdir,
    const float* __restrict__ dist_bias,
    const float* __restrict__ Wo, const float* __restrict__ W1, const float* __restrict__ W2,
    const float* __restrict__ Wg, const float* __restrict__ Wq, const float* __restrict__ Wk,
    const float* __restrict__ Wv, int l)
{
    __shared__ __align__(16) float sS[ATB*LDA];
    __shared__ __align__(16) float sH[ATB*LDA];
    __shared__ __align__(16) float sM[ATB*LDU];       // msg | weight buf B (4224 >= 4096)
    __shared__ __align__(16) float sVA[3][ATB*LDA];   // vec agg | FFN mids | weight buf C (6528 >= 4096)
    __shared__ __align__(16) float sW[4096];          // weight buf A
    __shared__ float sDS[ATB*24];

    const int tid = threadIdx.x;
    const int bswz = (blockIdx.x & 7) * (NBLK/8) + (blockIdx.x >> 3);
    const int a0 = bswz*ATB;
    const int gi = tid>>4, gj = tid&15;
    const int lrow = tid>>3, lsub = tid&7;
    const int wv = tid>>6, lane = tid&63;

    const float* Wo_l = Wo + l*4096;
    const float* Wg_l = Wg + l*4096;
    const float* Wc_l = Wvec + l*4096;
    const float* W1_l = W1 + l*8192;
    const float* W2_l = W2 + l*8192;
    const float* db_l = dist_bias + l*BINS*8;
    const float* wd_l = wdir + l*64;

    auto stageW = [&](const float* W, float* dst4) {
        const float4* src = (const float4*)W; float4* dst = (float4*)dst4;
        #pragma unroll
        for (int r = 0; r < 4; ++r) dst[tid + 256*r] = src[tid + 256*r];
    };
    auto stageW1h = [&](const float* W1l, int h, float* dst4) {
        const float4* src = (const float4*)W1l; float4* dst = (float4*)dst4;
        #pragma unroll
        for (int r = 0; r < 4; ++r) {
            int q = tid + 256*r;
            int row = q >> 4, c4i = q & 15;
            dst[q] = src[row*32 + h*16 + c4i];
        }
    };
    auto do_gemm = [&](const float* sA, int lda, const float* sWb, float4& C0, float4& C1) {
        const float* a0p = sA + gi*lda;
        const float* a1p = sA + (gi+16)*lda;
        const float* wr  = sWb + gj*4;
        f32x2 c0l = {C0.x, C0.y}, c0h = {C0.z, C0.w};
        f32x2 c1l = {C1.x, C1.y}, c1h = {C1.z, C1.w};
        #pragma unroll 8
        for (int k = 0; k < 64; ++k) {
            float av0 = a0p[k], av1 = a1p[k];
            float4 w = *(const float4*)(wr + k*64);
            f32x2 wl = {w.x, w.y}, wh = {w.z, w.w};
            f32x2 va0 = {av0, av0}, va1 = {av1, av1};
            c0l = __builtin_elementwise_fma(va0, wl, c0l);
            c0h = __builtin_elementwise_fma(va0, wh, c0h);
            c1l = __builtin_elementwise_fma(va1, wl, c1l);
            c1h = __builtin_elementwise_fma(va1, wh, c1h);
        }
        C0 = make_float4(c0l.x, c0l.y, c0h.x, c0h.y);
        C1 = make_float4(c1l.x, c1l.y, c1h.x, c1h.y);
    };
    auto do_ln = [&](const float* src, float* dst) {
        const float* sp = src + lrow*LDA + lsub*8;
        float v[8]; float s1 = 0.f;
        #pragma unroll
        for (int e = 0; e < 8; ++e) { v[e] = sp[e]; s1 += v[e]; }
        s1 += __shfl_xor(s1,1); s1 += __shfl_xor(s1,2); s1 += __shfl_xor(s1,4);
        float mean = s1*(1.0f/64.0f);
        float s2 = 0.f;
        #pragma unroll
        for (int e = 0; e < 8; ++e) { float t = v[e]-mean; s2 += t*t; }
        s2 += __shfl_xor(s2,1); s2 += __shfl_xor(s2,2); s2 += __shfl_xor(s2,4);
        float sc = 1.0f/sqrtf(s2*(1.0f/64.0f)+1e-5f);
        float* dp = dst + lrow*LDA + lsub*8;
        #pragma unroll
        for (int e = 0; e < 8; ++e) dp[e] = (v[e]-mean)*sc;
    };
    auto store_g = [&](float* base, float4 c0, float4 c1) {
        int g0 = a0+gi, g1 = a0+gi+16;
        if (g0 < NN) *(float4*)(base + (size_t)g0*64 + gj*4) = c0;
        if (g1 < NN) *(float4*)(base + (size_t)g1*64 + gj*4) = c1;
    };

    // ---- P0: load s ----
    {
        int ga = a0 + lrow;
        float4 z = make_float4(0,0,0,0);
        float4 x0 = z, x1 = z;
        if (ga < NN) {
            const float4* sp = (const float4*)(sg + (size_t)ga*64);
            x0 = sp[lsub*2]; x1 = sp[lsub*2+1];
        }
        float4* dp = (float4*)(sS + lrow*LDA);
        dp[lsub*2] = x0; dp[lsub*2+1] = x1;
    }
    stageW(Wo_l, sW);   // sW idle during attention; guarded by barrier 1

    // ---- P1: attention ----
    for (int aa = 0; aa < 8; ++aa) {
        int la = wv*8 + aa;
        int ga = a0 + la;
        if (ga >= NN) break;
        float qh = qin[(size_t)ga*64 + lane];
        float lg[KNB]; int nb[KNB];
        #pragma unroll
        for (int k = 0; k < KNB; ++k) {
            int j = nbr[ga*KNB + k];
            nb[k] = j;
            float t = qh * kin[(size_t)j*64 + lane];
            t += __shfl_xor(t,1); t += __shfl_xor(t,2); t += __shfl_xor(t,4);
            lg[k] = t*0.35355339059327373f + db_l[bins[ga*KNB+k]*8 + (lane>>3)];
        }
        float m = lg[0];
        #pragma unroll
        for (int k = 1; k < KNB; ++k) m = fmaxf(m, lg[k]);
        float ssum = 0.f;
        #pragma unroll
        for (int k = 0; k < KNB; ++k) { lg[k] = __expf(lg[k]-m); ssum += lg[k]; }
        float inv = 1.0f/ssum;
        float mh=0.f, b0=0.f, b1=0.f, b2=0.f, s0=0.f, s1=0.f, s2=0.f;
        if (l > 0) {
            #pragma unroll
            for (int k = 0; k < KNB; ++k) {
                float w = lg[k]*inv; int j = nb[k];
                mh += w * vfin[(size_t)j*64 + lane];
                b0 += w * vin[(size_t)j*64 + lane];
                b1 += w * vin[(size_t)N64 + (size_t)j*64 + lane];
                b2 += w * vin[2*(size_t)N64 + (size_t)j*64 + lane];
                s0 += w * dirn[ga*48 + k*3 + 0];
                s1 += w * dirn[ga*48 + k*3 + 1];
                s2 += w * dirn[ga*48 + k*3 + 2];
            }
            sVA[0][la*LDA + lane] = b0;
            sVA[1][la*LDA + lane] = b1;
            sVA[2][la*LDA + lane] = b2;
        } else {
            #pragma unroll
            for (int k = 0; k < KNB; ++k) {
                float w = lg[k]*inv; int j = nb[k];
                mh += w * vfin[(size_t)j*64 + lane];
                s0 += w * dirn[ga*48 + k*3 + 0];
                s1 += w * dirn[ga*48 + k*3 + 1];
                s2 += w * dirn[ga*48 + k*3 + 2];
            }
        }
        sM[la*LDU + lane] = mh;
        if ((lane & 7) == 0) {
            int hh = lane >> 3;
            sDS[la*24 + 0*8 + hh] = s0;
            sDS[la*24 + 1*8 + hh] = s1;
            sDS[la*24 + 2*8 + hh] = s2;
        }
    }
    __syncthreads();   // B1: P0 sS + attention sM/sVA/sDS + Wo staged

    // ---- P2: s += msg @ Wo ----
    {
        float4 c0 = *(float4*)(sS + gi*LDA + gj*4);
        float4 c1 = *(float4*)(sS + (gi+16)*LDA + gj*4);
        do_gemm(sM, LDU, sW, c0, c1);
        *(float4*)(sS + gi*LDA + gj*4)      = c0;
        *(float4*)(sS + (gi+16)*LDA + gj*4) = c1;
    }
    __syncthreads();   // B2: sS stable; done reading sM(msg), sW(Wo)

    // ---- P3: LN -> sH ; stage Wg->sW AND Wvec->sM ----
    do_ln(sS, sH);
    stageW(Wg_l, sW);
    stageW(Wc_l, sM);
    __syncthreads();   // B3: sH + Wg + Wc visible

    // ---- P4: gate + vector update (no internal barriers) ----
    {
        float4 g0 = make_float4(0,0,0,0), g1 = g0;
        do_gemm(sH, LDA, sW, g0, g1);
        g0.x=sigmoid_f(g0.x); g0.y=sigmoid_f(g0.y); g0.z=sigmoid_f(g0.z); g0.w=sigmoid_f(g0.w);
        g1.x=sigmoid_f(g1.x); g1.y=sigmoid_f(g1.y); g1.z=sigmoid_f(g1.z); g1.w=sigmoid_f(g1.w);
        float4 wd4 = *(const float4*)&wd_l[gj*4];
        int g0i = a0+gi, g1i = a0+gi+16;
        #pragma unroll
        for (int p = 0; p < 3; ++p) {
            float4 t0 = make_float4(0,0,0,0), t1 = t0;
            if (l > 0) do_gemm(sVA[p], LDA, sM, t0, t1);
            float sp0 = sDS[gi*24 + p*8 + (gj>>1)];
            float sp1 = sDS[(gi+16)*24 + p*8 + (gj>>1)];
            if (g0i < NN) {
                float4 vi = make_float4(0,0,0,0);
                if (l > 0) vi = *(const float4*)(vin + (size_t)p*N64 + (size_t)g0i*64 + gj*4);
                float4 o;
                o.x = (vi.x + t0.x + wd4.x*sp0)*g0.x;
                o.y = (vi.y + t0.y + wd4.y*sp0)*g0.y;
                o.z = (vi.z + t0.z + wd4.z*sp0)*g0.z;
                o.w = (vi.w + t0.w + wd4.w*sp0)*g0.w;
                *(float4*)(vout + (size_t)p*N64 + (size_t)g0i*64 + gj*4) = o;
            }
            if (g1i < NN) {
                float4 vi = make_float4(0,0,0,0);
                if (l > 0) vi = *(const float4*)(vin + (size_t)p*N64 + (size_t)g1i*64 + gj*4);
                float4 o;
                o.x = (vi.x + t1.x + wd4.x*sp1)*g1.x;
                o.y = (vi.y + t1.y + wd4.y*sp1)*g1.y;
                o.z = (vi.z + t1.z + wd4.z*sp1)*g1.z;
                o.w = (vi.w + t1.w + wd4.w*sp1)*g1.w;
                *(float4*)(vout + (size_t)p*N64 + (size_t)g1i*64 + gj*4) = o;
            }
        }
    }
    __syncthreads();   // B4: done reading sW(Wg), sM(Wc), sVA, sDS (sH still live for P5)

    // ---- P5: FFN, both halves staged at once; mids in sVA[0]/sVA[1] ----
    stageW1h(W1_l, 0, sW);
    stageW1h(W1_l, 1, sM);
    __syncthreads();   // B5: W1 halves visible
    float4 u0a, u1a, u0b, u1b;
    {
        float4 c0 = make_float4(0,0,0,0), c1 = c0;
        do_gemm(sH, LDA, sW, c0, c1);
        u0a.x=gelu_f(c0.x); u0a.y=gelu_f(c0.y); u0a.z=gelu_f(c0.z); u0a.w=gelu_f(c0.w);
        u1a.x=gelu_f(c1.x); u1a.y=gelu_f(c1.y); u1a.z=gelu_f(c1.z); u1a.w=gelu_f(c1.w);
    }
    {
        float4 c0 = make_float4(0,0,0,0), c1 = c0;
        do_gemm(sH, LDA, sM, c0, c1);
        u0b.x=gelu_f(c0.x); u0b.y=gelu_f(c0.y); u0b.z=gelu_f(c0.z); u0b.w=gelu_f(c0.w);
        u1b.x=gelu_f(c1.x); u1b.y=gelu_f(c1.y); u1b.z=gelu_f(c1.z); u1b.w=gelu_f(c1.w);
    }
    // mids -> sVA planes (sVA free after B4; writes race nothing: sW/sM only read)
    *(float4*)(sVA[0] + gi*LDA + gj*4)      = u0a;
    *(float4*)(sVA[0] + (gi+16)*LDA + gj*4) = u1a;
    *(float4*)(sVA[1] + gi*LDA + gj*4)      = u0b;
    *(float4*)(sVA[1] + (gi+16)*LDA + gj*4) = u1b;
    __syncthreads();   // B6: mids visible; done reading sW/sM(W1)
    stageW(W2_l, sW);
    stageW(W2_l + 4096, sM);
    __syncthreads();   // B7: W2 halves visible
    {
        float4 c0 = *(float4*)(sS + gi*LDA + gj*4);
        float4 c1 = *(float4*)(sS + (gi+16)*LDA + gj*4);
        do_gemm(sVA[0], LDA, sW, c0, c1);
        do_gemm(sVA[1], LDA, sM, c0, c1);
        *(float4*)(sS + gi*LDA + gj*4)      = c0;
        *(float4*)(sS + (gi+16)*LDA + gj*4) = c1;
    }
    __syncthreads();   // B8: sS stable; done reading sW/sM(W2), sVA(mids)

    // ---- P6: next-layer q/k/vf (single staged phase) or pooling ----
    if (l < LAYERS-1) {
        do_ln(sS, sH);
        stageW(Wk + (l+1)*4096, sW);
        stageW(Wv + (l+1)*4096, sM);
        stageW(Wq + (l+1)*4096, (float*)sVA);
        __syncthreads();   // B9: sH + Wk/Wv/Wq visible
        { float4 c0 = make_float4(0,0,0,0), c1 = c0; do_gemm(sH, LDA, sW, c0, c1); store_g(kout, c0, c1); }
        { float4 c0 = make_float4(0,0,0,0), c1 = c0; do_gemm(sH, LDA, sM, c0, c1); store_g(vfout, c0, c1); }
        { float4 c0 = make_float4(0,0,0,0), c1 = c0; do_gemm(sH, LDA, (const float*)sVA, c0, c1); store_g(qout, c0, c1); }
        {
            int ga = a0 + lrow;
            if (ga < NN) {
                float4* dp = (float4*)(sg + (size_t)ga*64);
                const float4* sp = (const float4*)(sS + lrow*LDA);
                dp[lsub*2] = sp[lsub*2]; dp[lsub*2+1] = sp[lsub*2+1];
            }
        }
    } else {
        int ga = a0 + lrow;
        if (ga < NN) {
            int r = ridx[n2o[ga]];
            #pragma unroll
            for (int e = 0; e < 8; ++e)
                atomicAdd(&resb[r*64 + lsub*8 + e], sS[lrow*LDA + lsub*8 + e]);
        }
    }
}

// ---------------- head ----------------
__global__ void head_kernel(const float* __restrict__ res, const float* __restrict__ Wout,
                            const float* __restrict__ bout, float* __restrict__ out, int r_total) {
    int wave = threadIdx.x >> 6, lane = threadIdx.x & 63;
    int r = blockIdx.x*4 + wave;
    if (r >= r_total) return;
    float p = res[r*HID + lane] * (1.0f/APR);
    float o0 = p * Wout[lane*2 + 0];
    float o1 = p * Wout[lane*2 + 1];
    #pragma unroll
    for (int off = 1; off < 64; off <<= 1) { o0 += __shfl_xor(o0, off); o1 += __shfl_xor(o1, off); }
    if (lane == 0) { out[r*2+0] = o0 + bout[0]; out[r*2+1] = o1 + bout[1]; }
}

// ---------------- launcher ----------------
extern "C" void kernel_launch(void* const* d_in, const int* in_sizes, int n_in,
                              void* d_out, int out_size, void* d_ws, size_t ws_size,
                              hipStream_t stream) {
    const float* coords    = (const float*)d_in[0];
    const int*   atom_ids  = (const int*)d_in[1];
    const int*   res_ids   = (const int*)d_in[2];
    const int*   elem_ids  = (const int*)d_in[3];
    const int*   ridx      = (const int*)d_in[4];
    const float* emb_atom  = (const float*)d_in[5];
    const float* emb_res   = (const float*)d_in[6];
    const float* emb_elem  = (const float*)d_in[7];
    const float* Win       = (const float*)d_in[8];
    const float* Wq        = (const float*)d_in[9];
    const float* Wk        = (const float*)d_in[10];
    const float* Wv        = (const float*)d_in[11];
    const float* Wvec      = (const float*)d_in[12];
    const float* wdir      = (const float*)d_in[13];
    const float* dist_bias = (const float*)d_in[14];
    const float* Wo        = (const float*)d_in[15];
    const float* W1        = (const float*)d_in[16];
    const float* W2        = (const float*)d_in[17];
    const float* Wg        = (const float*)d_in[18];
    const float* Wout      = (const float*)d_in[19];
    const float* bout      = (const float*)d_in[20];
    float* out = (float*)d_out;

    float* ws = (float*)d_ws;
    float* qA = ws + OFF_QA;  float* kA = ws + OFF_KA;  float* fA = ws + OFF_FA;
    float* qB = ws + OFF_QB;  float* kB = ws + OFF_KB;  float* fB = ws + OFF_FB;
    float* vA = ws + OFF_VA;  float* vB = ws + OFF_VB;
    float* sg = ws + OFF_S;
    float* dirn_s = ws + OFF_DIRNS;
    float4* c4  = (float4*)(ws + OFF_C4);
    float4* c4s = (float4*)(ws + OFF_C4S);
    float* resb = ws + OFF_RES;
    int* nbr_s  = (int*)(ws + OFF_NBRS);
    int* bins_s = (int*)(ws + OFF_BINSS);
    int* o2n    = (int*)(ws + OFF_O2N);
    int* n2o    = (int*)(ws + OFF_N2O);
    int* cellid = (int*)(ws + OFF_CELL);
    int* hist   = (int*)(ws + OFF_HIST);
    int* cnt    = (int*)(ws + OFF_CNT);
    int* baseb  = (int*)(ws + OFF_BASE);

    hipMemsetAsync(hist, 0, 2*4096*sizeof(int), stream);

    pad_cell_kernel<<<(NN+255)/256, 256, 0, stream>>>(coords, c4, cellid, hist, resb, NN);
    scan_kernel<<<1, 256, 0, stream>>>(hist, baseb);
    scatter_kernel<<<(NN+255)/256, 256, 0, stream>>>(cellid, baseb, cnt, o2n, n2o, c4, c4s, NN);
    knn_grid_kernel<<<(NN+3)/4, 256, 0, stream>>>(c4s, baseb, hist, n2o, o2n, nbr_s, bins_s, dirn_s, NN);

    prologue_kernel<<<NBLK, 256, 0, stream>>>(atom_ids, res_ids, elem_ids, n2o,
                                              emb_atom, emb_res, emb_elem,
                                              Win, Wq, Wk, Wv, sg, qA, kA, fA);
    for (int l = 0; l < LAYERS; ++l) {
        int p = l & 1;
        const float* qin = p ? qB : qA;  float* qout = p ? qA : qB;
        const float* kin = p ? kB : kA;  float* kout = p ? kA : kB;
        const float* fin = p ? fB : fA;  float* fout = p ? fA : fB;
        const float* vin = p ? vB : vA;  float* vout = p ? vA : vB;
        layer_kernel<<<NBLK, 256, 0, stream>>>(qin, kin, fin, qout, kout, fout,
                                               vin, vout, sg, dirn_s, nbr_s, bins_s,
                                               resb, ridx, n2o,
                                               Wvec, wdir, dist_bias,
                                               Wo, W1, W2, Wg, Wq, Wk, Wv, l);
    }
    head_kernel<<<(RR+3)/4, 256, 0, stream>>>(resb, Wout, bout, out, RR);
}

// Round 10
// 526.438 us; speedup vs baseline: 1.0267x; 1.0267x over previous
//
#include <hip/hip_runtime.h>
#include <cfloat>

// ---- problem dims ----
#define NN    16380
#define RR    819
#define APR   20
#define KNB   16
#define HID   64
#define LAYERS 6
#define BINS  100
#define N64   (NN*HID)

// ---- geometry ----
#define ATB   32
#define NBLK  512               // 512*32 = 16384 >= NN
#define LDA   68
#define LDU   132
#define CSIZE 4.375f            // 70/16

// ---- workspace float offsets ----
#define OFF_QA    0
#define OFF_KA    (1*N64)
#define OFF_FA    (2*N64)
#define OFF_QB    (3*N64)
#define OFF_KB    (4*N64)
#define OFF_FB    (5*N64)
#define OFF_VA    (6*N64)           // 3 planes
#define OFF_VB    (9*N64)           // 3 planes
#define OFF_S     (12*N64)
#define OFF_DIRNS (13*N64)          // N*48 (sorted space)
#define OFF_C4    (OFF_DIRNS + NN*48)
#define OFF_C4S   (OFF_C4 + NN*4)
#define OFF_RES   (OFF_C4S + NN*4)
#define OFF_NBRS  (OFF_RES + RR*64)    // int N*16 (sorted space)
#define OFF_BINSS (OFF_NBRS + NN*16)   // int N*16
#define OFF_O2N   (OFF_BINSS + NN*16)  // int N
#define OFF_N2O   (OFF_O2N + NN)       // int N
#define OFF_CELL  (OFF_N2O + NN)       // int N
#define OFF_HIST  (OFF_CELL + NN)      // int 4096
#define OFF_CNT   (OFF_HIST + 4096)    // int 4096 (adjacent: one memset covers both)
#define OFF_BASE  (OFF_CNT + 4096)     // int 4096

typedef unsigned long long u64;
#define U64MAX 0xFFFFFFFFFFFFFFFFull

// Round-8 fast transcendentals (kept; -43us). Round-10: pk-FMA REVERTED (round-9
// A/B: neutral, +8us noise -- GEMM FMAs are independent ops already latency-hidden;
// the exp win was about killing long dependent chains, not issue count).
__device__ __forceinline__ float gelu_f(float x) {
    float x3 = x*x*x;
    float z = 0.7978845608028654f*(x + 0.044715f*x3);
    float t = 1.0f - 2.0f/(__expf(2.0f*z) + 1.0f);   // tanh(z)
    return 0.5f*x*(1.0f+t);
}
__device__ __forceinline__ float sigmoid_f(float x) {
    return 1.0f/(1.0f + __expf(-x));
}
__device__ __forceinline__ int spread3(int x) {   // 4-bit -> every 3rd bit
    return (x&1) | ((x&2)<<2) | ((x&4)<<4) | ((x&8)<<6);
}
__device__ __forceinline__ unsigned sortable_u32(float f) {
    unsigned u = __float_as_uint(f);
    return u ^ ((u & 0x80000000u) ? 0xFFFFFFFFu : 0x80000000u);
}

// ---------------- fused pad + cell-id + histogram + resb zero ----------------
__global__ void pad_cell_kernel(const float* __restrict__ coords, float4* __restrict__ c4,
                                int* __restrict__ cellid, int* __restrict__ hist,
                                float* __restrict__ resb, int n) {
    int i = blockIdx.x*256 + threadIdx.x;
    for (int j = i; j < RR*HID; j += 16384) resb[j] = 0.f;
    if (i >= n) return;
    float x = coords[3*i], y = coords[3*i+1], z = coords[3*i+2];
    float sq = __fadd_rn(__fadd_rn(__fmul_rn(x,x), __fmul_rn(y,y)), __fmul_rn(z,z));
    c4[i] = make_float4(x, y, z, sq);
    int cx = min(15, max(0, (int)(x * (16.0f/70.0f))));
    int cy = min(15, max(0, (int)(y * (16.0f/70.0f))));
    int cz = min(15, max(0, (int)(z * (16.0f/70.0f))));
    int m = spread3(cx) | (spread3(cy)<<1) | (spread3(cz)<<2);
    cellid[i] = m;
    atomicAdd(&hist[m], 1);
}
__global__ void scan_kernel(const int* __restrict__ hist, int* __restrict__ base) {
    __shared__ int part[256];
    int t = threadIdx.x;
    int loc[16]; int s = 0;
    #pragma unroll
    for (int e = 0; e < 16; ++e) { loc[e] = s; s += hist[t*16+e]; }
    part[t] = s;
    __syncthreads();
    if (t == 0) { int acc = 0; for (int i = 0; i < 256; ++i) { int v = part[i]; part[i] = acc; acc += v; } }
    __syncthreads();
    int off = part[t];
    #pragma unroll
    for (int e = 0; e < 16; ++e) base[t*16+e] = off + loc[e];
}
__global__ void scatter_kernel(const int* __restrict__ cellid, const int* __restrict__ base,
                               int* __restrict__ cnt, int* __restrict__ o2n,
                               int* __restrict__ n2o, const float4* __restrict__ c4,
                               float4* __restrict__ c4s, int n) {
    int i = blockIdx.x*256 + threadIdx.x;
    if (i >= n) return;
    int m = cellid[i];
    int pos = base[m] + atomicAdd(&cnt[m], 1);
    o2n[i] = pos; n2o[pos] = i;
    c4s[pos] = c4[i];
}

// ---------------- grid kNN: bitonic + round-10 exact per-cell distance cull ----------------
// Round-10: ~half the atoms fail the R=1 exit (d16 ~ cell size) and swept the
// full 98-cell R=2 ring (~400 candidates). Most ring cells have point-to-cell
// min-dist^2 far above the current vmax. Cull: skip cell iff
// mind2(query_point, cell_box) - 0.05 > vmax_d2. Provably conservative: any
// point in a culled cell has key > vmax (vmax only shrinks; 0.05 >> d^2
// rounding ~1e-3), so it could never enter the top-16. vmax==U64MAX -> keep all.
#define SCRATCH 1024
__global__ __launch_bounds__(256) void knn_grid_kernel(
    const float4* __restrict__ c4s, const int* __restrict__ base, const int* __restrict__ hist,
    const int* __restrict__ n2o, const int* __restrict__ o2n,
    int* __restrict__ nbr, int* __restrict__ binsO, float* __restrict__ dirn, int n)
{
    __shared__ int sIdx[4][SCRATCH];
    int tid = threadIdx.x;
    int wv = tid >> 6, lane = tid & 63;
    int i = blockIdx.x*4 + wv;
    bool valid = i < n;
    int ii = valid ? i : 0;
    float4 cd = c4s[ii];
    float sqd = cd.w;
    int cx = min(15, max(0, (int)(cd.x * (16.0f/70.0f))));
    int cy = min(15, max(0, (int)(cd.y * (16.0f/70.0f))));
    int cz = min(15, max(0, (int)(cd.z * (16.0f/70.0f))));
    u64 dlist = U64MAX;
    u64 vmax  = U64MAX;
    int* sidx = sIdx[wv];

    auto compute_pk = [&](int idx) -> u64 {
        if (idx == i) return U64MAX;
        float4 cc = c4s[idx];
        float dt = __fmul_rn(cd.x, cc.x);
        dt = __fmaf_rn(cd.y, cc.y, dt);
        dt = __fmaf_rn(cd.z, cc.z, dt);
        float key = __fsub_rn(__fadd_rn(sqd, cc.w), __fmul_rn(2.0f, dt));
        int org = n2o[idx];
        return ((u64)sortable_u32(key) << 32) | (unsigned)org;
    };

    auto process_batch = [&](int M) {
        if (M <= 0) return;
        for (int c0 = 0; c0 < M; c0 += 64) {
            int p = c0 + lane;
            u64 v = (p < M) ? compute_pk(sidx[p]) : U64MAX;
            // ---- pre-sort rejection: wave-min of chunk vs current 16th-best ----
            u64 mn = v;
            #pragma unroll
            for (int off = 1; off < 64; off <<= 1) {
                u64 o = __shfl_xor(mn, off);
                mn = (o < mn) ? o : mn;
            }
            if (mn >= vmax) continue;       // wave-uniform after butterfly
            // ---- bitonic sort: 64 keys ascending across lanes ----
            #pragma unroll
            for (int k = 2; k <= 64; k <<= 1) {
                #pragma unroll
                for (int j = k >> 1; j > 0; j >>= 1) {
                    u64 o = __shfl_xor(v, j);
                    bool keepmin = (((lane & j) == 0) == ((lane & k) == 0));
                    u64 mnn = (v < o) ? v : o;
                    u64 mxx = (v < o) ? o : v;
                    v = keepmin ? mnn : mxx;
                }
            }
            // ---- merge: [dlist asc lanes0-15 | chunk top16 desc lanes16-31] ----
            u64 bm = __shfl(v, (31 - lane) & 63);
            u64 m = (lane < 16) ? dlist : bm;
            #pragma unroll
            for (int j = 16; j > 0; j >>= 1) {
                u64 o = __shfl_xor(m, j);
                u64 mnn = (m < o) ? m : o;
                u64 mxx = (m < o) ? o : m;
                m = ((lane & j) == 0) ? mnn : mxx;
            }
            if (lane < 16) dlist = m;
            vmax = __shfl(dlist, 15);
        }
    };

    for (int R = 1; R <= 16; ++R) {
        int side = 2*R+1;
        int ncell = side*side*side;
        int M = 0;
        for (int t0 = 0; t0 < ncell; t0 += 64) {
            // conservative current 16th-best d^2 (vmax only shrinks, so any
            // cell culled against this value stays culled-correct)
            float vmax_d2 = 3.4e38f;
            if (vmax != U64MAX) {
                unsigned s = (unsigned)(vmax >> 32);
                unsigned bb = (s & 0x80000000u) ? (s ^ 0x80000000u) : ~s;
                vmax_d2 = __uint_as_float(bb);
            }
            int t = t0 + lane;
            int cnt = 0, b = 0;
            if (t < ncell) {
                int dxc = t % side - R;
                int dyc = (t/side) % side - R;
                int dzc = t/(side*side) - R;
                int ch = max(abs(dxc), max(abs(dyc), abs(dzc)));
                bool use = (R == 1) || (ch == R);
                int x = cx+dxc, y = cy+dyc, z = cz+dzc;
                if (use && x>=0 && x<16 && y>=0 && y<16 && z>=0 && z<16) {
                    // exact point-to-cell-box min distance cull (open boxes at
                    // the clamped boundary cells)
                    float lox = (x==0)  ? -1e30f : x*CSIZE;
                    float hix = (x==15) ?  1e30f : (x+1)*CSIZE;
                    float loy = (y==0)  ? -1e30f : y*CSIZE;
                    float hiy = (y==15) ?  1e30f : (y+1)*CSIZE;
                    float loz = (z==0)  ? -1e30f : z*CSIZE;
                    float hiz = (z==15) ?  1e30f : (z+1)*CSIZE;
                    float gx = fmaxf(0.f, fmaxf(lox - cd.x, cd.x - hix));
                    float gy = fmaxf(0.f, fmaxf(loy - cd.y, cd.y - hiy));
                    float gz = fmaxf(0.f, fmaxf(loz - cd.z, cd.z - hiz));
                    float mind2 = gx*gx + gy*gy + gz*gz;
                    if (mind2 - 0.05f <= vmax_d2) {
                        int m = spread3(x) | (spread3(y)<<1) | (spread3(z)<<2);
                        cnt = hist[m]; b = base[m];
                    }
                }
            }
            int incl = cnt;
            #pragma unroll
            for (int o = 1; o < 64; o <<= 1) { int v = __shfl_up(incl, o); if (lane >= o) incl += v; }
            int excl = incl - cnt;
            int tot = __shfl(incl, 63);
            if (M + tot > SCRATCH) { process_batch(M); M = 0; }
            for (int e = 0; e < cnt; ++e) {
                int pos = M + excl + e;
                if (pos < SCRATCH) sidx[pos] = b + e;
            }
            M = min(M + tot, SCRATCH);
        }
        process_batch(M);
        float rim = (float)R * CSIZE;
        unsigned thS = sortable_u32(rim*rim - 0.05f);
        if ((unsigned)(vmax >> 32) < thS) break;
    }
    if (valid && lane < 16) {
        int org = (int)(dlist & 0xFFFFFFFFull);
        int src = o2n[org];
        float4 cs = c4s[src];
        float dx = __fsub_rn(cd.x, cs.x);
        float dy = __fsub_rn(cd.y, cs.y);
        float dz = __fsub_rn(cd.z, cs.z);
        float ss = __fadd_rn(__fadd_rn(__fmul_rn(dx,dx), __fmul_rn(dy,dy)),
                             __fmul_rn(dz,dz));
        float dd = __fsqrt_rn(__fadd_rn(ss, 1e-12f));
        nbr[i*KNB + lane] = src;
        float bf = __fmul_rn(__fdiv_rn(dd, 10.0f), 100.0f);
        int b = (int)bf;
        b = min(max(b, 0), BINS-1);
        binsO[i*KNB + lane] = b;
        dirn[i*48 + lane*3 + 0] = __fdiv_rn(dx, dd);
        dirn[i*48 + lane*3 + 1] = __fdiv_rn(dy, dd);
        dirn[i*48 + lane*3 + 2] = __fdiv_rn(dz, dd);
    }
}

// ---------------- prologue: round-8 verbatim (256 threads, 2 rows/thread) ----------------
__global__ __launch_bounds__(256) void prologue_kernel(
    const int* __restrict__ aid, const int* __restrict__ rid, const int* __restrict__ eid,
    const int* __restrict__ n2o,
    const float* __restrict__ ea, const float* __restrict__ er, const float* __restrict__ ee,
    const float* __restrict__ Win, const float* __restrict__ Wq, const float* __restrict__ Wk,
    const float* __restrict__ Wv,
    float* __restrict__ sg, float* __restrict__ qout, float* __restrict__ kout,
    float* __restrict__ vfout)
{
    __shared__ __align__(16) float sS[ATB*LDA];
    __shared__ __align__(16) float sH[ATB*LDA];
    __shared__ __align__(16) float sW[4096];
    const int tid = threadIdx.x;
    const int a0 = blockIdx.x*ATB;
    const int gi = tid>>4, gj = tid&15;
    const int lrow = tid>>3, lsub = tid&7;

    auto stageW = [&](const float* W) {
        const float4* src = (const float4*)W; float4* dst = (float4*)sW;
        #pragma unroll
        for (int r = 0; r < 4; ++r) dst[tid + 256*r] = src[tid + 256*r];
    };
    auto do_gemm = [&](const float* sA, float4& c0, float4& c1) {
        const float* a0p = sA + gi*LDA;
        const float* a1p = sA + (gi+16)*LDA;
        const float* wr  = sW + gj*4;
        #pragma unroll 8
        for (int k = 0; k < 64; ++k) {
            float av0 = a0p[k], av1 = a1p[k];
            float4 w = *(const float4*)(wr + k*64);
            c0.x = fmaf(av0,w.x,c0.x); c0.y = fmaf(av0,w.y,c0.y);
            c0.z = fmaf(av0,w.z,c0.z); c0.w = fmaf(av0,w.w,c0.w);
            c1.x = fmaf(av1,w.x,c1.x); c1.y = fmaf(av1,w.y,c1.y);
            c1.z = fmaf(av1,w.z,c1.z); c1.w = fmaf(av1,w.w,c1.w);
        }
    };
    auto do_ln = [&](const float* src, float* dst) {
        const float* sp = src + lrow*LDA + lsub*8;
        float v[8]; float s1 = 0.f;
        #pragma unroll
        for (int e = 0; e < 8; ++e) { v[e] = sp[e]; s1 += v[e]; }
        s1 += __shfl_xor(s1,1); s1 += __shfl_xor(s1,2); s1 += __shfl_xor(s1,4);
        float mean = s1*(1.0f/64.0f);
        float s2 = 0.f;
        #pragma unroll
        for (int e = 0; e < 8; ++e) { float t = v[e]-mean; s2 += t*t; }
        s2 += __shfl_xor(s2,1); s2 += __shfl_xor(s2,2); s2 += __shfl_xor(s2,4);
        float sc = 1.0f/sqrtf(s2*(1.0f/64.0f)+1e-5f);
        float* dp = dst + lrow*LDA + lsub*8;
        #pragma unroll
        for (int e = 0; e < 8; ++e) dp[e] = (v[e]-mean)*sc;
    };
    auto store_g = [&](float* base, float4 c0, float4 c1) {
        int g0 = a0+gi, g1 = a0+gi+16;
        if (g0 < NN) *(float4*)(base + (size_t)g0*64 + gj*4) = c0;
        if (g1 < NN) *(float4*)(base + (size_t)g1*64 + gj*4) = c1;
    };

    {   // feat -> sH  (overlapped with Win staging; both guarded by next sync)
        int ga = a0 + lrow;
        int io = (ga < NN) ? n2o[ga] : 0;
        #pragma unroll
        for (int e = 0; e < 8; ++e) {
            int c = lsub*8 + e;
            float x = 0.f;
            if (ga < NN) {
                if (c < 32)      x = ea[aid[io]*32 + c];
                else if (c < 48) x = er[rid[io]*16 + (c-32)];
                else             x = ee[eid[io]*16 + (c-48)];
            }
            sH[lrow*LDA + c] = x;
        }
    }
    stageW(Win);
    __syncthreads();
    {
        float4 c0 = make_float4(0,0,0,0), c1 = c0;
        do_gemm(sH, c0, c1);
        *(float4*)(sS + gi*LDA + gj*4)      = c0;
        *(float4*)(sS + (gi+16)*LDA + gj*4) = c1;
        store_g(sg, c0, c1);
    }
    __syncthreads();                 // all done with sH(feat), sW(Win); sS written
    do_ln(sS, sH);                   // overlap LN with Wk staging
    stageW(Wk);
    __syncthreads();
    { float4 c0 = make_float4(0,0,0,0), c1 = c0; do_gemm(sH, c0, c1); store_g(kout, c0, c1); }
    __syncthreads();
    stageW(Wv); __syncthreads();
    { float4 c0 = make_float4(0,0,0,0), c1 = c0; do_gemm(sH, c0, c1); store_g(vfout, c0, c1); }
    __syncthreads();
    stageW(Wq); __syncthreads();
    { float4 c0 = make_float4(0,0,0,0), c1 = c0; do_gemm(sH, c0, c1); store_g(qout, c0, c1); }
}

// ---------------- fused layer kernel: round-8 verbatim (best measured, 532us total) ----------------
__global__ __launch_bounds__(256) void layer_kernel(
    const float* __restrict__ qin, const float* __restrict__ kin, const float* __restrict__ vfin,
    float* __restrict__ qout, float* __restrict__ kout, float* __restrict__ vfout,
    const float* __restrict__ vin, float* __restrict__ vout,
    float* __restrict__ sg, const float* __restrict__ dirn,
    const int* __restrict__ nbr, const int* __restrict__ bins,
    float* __restrict__ resb, const int* __restrict__ ridx, const int* __restrict__ n2o,
    const float* __restrict__ Wvec, const float* __restrict__ wdir,
    const float* __restrict__ dist_bias,
    const float* __restrict__ Wo, const float* __restrict__ W1, const float* __restrict__ W2,
    const float* __restrict__ Wg, const float* __restrict__ Wq, const float* __restrict__ Wk,
    const float* __restrict__ Wv, int l)
{
    __shared__ __align__(16) float sS[ATB*LDA];
    __shared__ __align__(16) float sH[ATB*LDA];
    __shared__ __align__(16) float sM[ATB*LDU];       // msg | weight buf B (4224 >= 4096)
    __shared__ __align__(16) float sVA[3][ATB*LDA];   // vec agg | FFN mids | weight buf C (6528 >= 4096)
    __shared__ __align__(16) float sW[4096];          // weight buf A
    __shared__ float sDS[ATB*24];

    const int tid = threadIdx.x;
    const int bswz = (blockIdx.x & 7) * (NBLK/8) + (blockIdx.x >> 3);
    const int a0 = bswz*ATB;
    const int gi = tid>>4, gj = tid&15;
    const int lrow = tid>>3, lsub = tid&7;
    const int wv = tid>>6, lane = tid&63;

    const float* Wo_l = Wo + l*4096;
    const float* Wg_l = Wg + l*4096;
    const float* Wc_l = Wvec + l*4096;
    const float* W1_l = W1 + l*8192;
    const float* W2_l = W2 + l*8192;
    const float* db_l = dist_bias + l*BINS*8;
    const float* wd_l = wdir + l*64;

    auto stageW = [&](const float* W, float* dst4) {
        const float4* src = (const float4*)W; float4* dst = (float4*)dst4;
        #pragma unroll
        for (int r = 0; r < 4; ++r) dst[tid + 256*r] = src[tid + 256*r];
    };
    auto stageW1h = [&](const float* W1l, int h, float* dst4) {
        const float4* src = (const float4*)W1l; float4* dst = (float4*)dst4;
        #pragma unroll
        for (int r = 0; r < 4; ++r) {
            int q = tid + 256*r;
            int row = q >> 4, c4i = q & 15;
            dst[q] = src[row*32 + h*16 + c4i];
        }
    };
    auto do_gemm = [&](const float* sA, int lda, const float* sWb, float4& c0, float4& c1) {
        const float* a0p = sA + gi*lda;
        const float* a1p = sA + (gi+16)*lda;
        const float* wr  = sWb + gj*4;
        #pragma unroll 8
        for (int k = 0; k < 64; ++k) {
            float av0 = a0p[k], av1 = a1p[k];
            float4 w = *(const float4*)(wr + k*64);
            c0.x = fmaf(av0,w.x,c0.x); c0.y = fmaf(av0,w.y,c0.y);
            c0.z = fmaf(av0,w.z,c0.z); c0.w = fmaf(av0,w.w,c0.w);
            c1.x = fmaf(av1,w.x,c1.x); c1.y = fmaf(av1,w.y,c1.y);
            c1.z = fmaf(av1,w.z,c1.z); c1.w = fmaf(av1,w.w,c1.w);
        }
    };
    auto do_ln = [&](const float* src, float* dst) {
        const float* sp = src + lrow*LDA + lsub*8;
        float v[8]; float s1 = 0.f;
        #pragma unroll
        for (int e = 0; e < 8; ++e) { v[e] = sp[e]; s1 += v[e]; }
        s1 += __shfl_xor(s1,1); s1 += __shfl_xor(s1,2); s1 += __shfl_xor(s1,4);
        float mean = s1*(1.0f/64.0f);
        float s2 = 0.f;
        #pragma unroll
        for (int e = 0; e < 8; ++e) { float t = v[e]-mean; s2 += t*t; }
        s2 += __shfl_xor(s2,1); s2 += __shfl_xor(s2,2); s2 += __shfl_xor(s2,4);
        float sc = 1.0f/sqrtf(s2*(1.0f/64.0f)+1e-5f);
        float* dp = dst + lrow*LDA + lsub*8;
        #pragma unroll
        for (int e = 0; e < 8; ++e) dp[e] = (v[e]-mean)*sc;
    };
    auto store_g = [&](float* base, float4 c0, float4 c1) {
        int g0 = a0+gi, g1 = a0+gi+16;
        if (g0 < NN) *(float4*)(base + (size_t)g0*64 + gj*4) = c0;
        if (g1 < NN) *(float4*)(base + (size_t)g1*64 + gj*4) = c1;
    };

    // ---- P0: load s ----
    {
        int ga = a0 + lrow;
        float4 z = make_float4(0,0,0,0);
        float4 x0 = z, x1 = z;
        if (ga < NN) {
            const float4* sp = (const float4*)(sg + (size_t)ga*64);
            x0 = sp[lsub*2]; x1 = sp[lsub*2+1];
        }
        float4* dp = (float4*)(sS + lrow*LDA);
        dp[lsub*2] = x0; dp[lsub*2+1] = x1;
    }
    stageW(Wo_l, sW);   // sW idle during attention; guarded by barrier 1

    // ---- P1: attention ----
    for (int aa = 0; aa < 8; ++aa) {
        int la = wv*8 + aa;
        int ga = a0 + la;
        if (ga >= NN) break;
        float qh = qin[(size_t)ga*64 + lane];
        float lg[KNB]; int nb[KNB];
        #pragma unroll
        for (int k = 0; k < KNB; ++k) {
            int j = nbr[ga*KNB + k];
            nb[k] = j;
            float t = qh * kin[(size_t)j*64 + lane];
            t += __shfl_xor(t,1); t += __shfl_xor(t,2); t += __shfl_xor(t,4);
            lg[k] = t*0.35355339059327373f + db_l[bins[ga*KNB+k]*8 + (lane>>3)];
        }
        float m = lg[0];
        #pragma unroll
        for (int k = 1; k < KNB; ++k) m = fmaxf(m, lg[k]);
        float ssum = 0.f;
        #pragma unroll
        for (int k = 0; k < KNB; ++k) { lg[k] = __expf(lg[k]-m); ssum += lg[k]; }
        float inv = 1.0f/ssum;
        float mh=0.f, b0=0.f, b1=0.f, b2=0.f, s0=0.f, s1=0.f, s2=0.f;
        if (l > 0) {
            #pragma unroll
            for (int k = 0; k < KNB; ++k) {
                float w = lg[k]*inv; int j = nb[k];
                mh += w * vfin[(size_t)j*64 + lane];
                b0 += w * vin[(size_t)j*64 + lane];
                b1 += w * vin[(size_t)N64 + (size_t)j*64 + lane];
                b2 += w * vin[2*(size_t)N64 + (size_t)j*64 + lane];
                s0 += w * dirn[ga*48 + k*3 + 0];
                s1 += w * dirn[ga*48 + k*3 + 1];
                s2 += w * dirn[ga*48 + k*3 + 2];
            }
            sVA[0][la*LDA + lane] = b0;
            sVA[1][la*LDA + lane] = b1;
            sVA[2][la*LDA + lane] = b2;
        } else {
            #pragma unroll
            for (int k = 0; k < KNB; ++k) {
                float w = lg[k]*inv; int j = nb[k];
                mh += w * vfin[(size_t)j*64 + lane];
                s0 += w * dirn[ga*48 + k*3 + 0];
                s1 += w * dirn[ga*48 + k*3 + 1];
                s2 += w * dirn[ga*48 + k*3 + 2];
            }
        }
        sM[la*LDU + lane] = mh;
        if ((lane & 7) == 0) {
            int hh = lane >> 3;
            sDS[la*24 + 0*8 + hh] = s0;
            sDS[la*24 + 1*8 + hh] = s1;
            sDS[la*24 + 2*8 + hh] = s2;
        }
    }
    __syncthreads();   // B1: P0 sS + attention sM/sVA/sDS + Wo staged

    // ---- P2: s += msg @ Wo ----
    {
        float4 c0 = *(float4*)(sS + gi*LDA + gj*4);
        float4 c1 = *(float4*)(sS + (gi+16)*LDA + gj*4);
        do_gemm(sM, LDU, sW, c0, c1);
        *(float4*)(sS + gi*LDA + gj*4)      = c0;
        *(float4*)(sS + (gi+16)*LDA + gj*4) = c1;
    }
    __syncthreads();   // B2: sS stable; done reading sM(msg), sW(Wo)

    // ---- P3: LN -> sH ; stage Wg->sW AND Wvec->sM ----
    do_ln(sS, sH);
    stageW(Wg_l, sW);
    stageW(Wc_l, sM);
    __syncthreads();   // B3: sH + Wg + Wc visible

    // ---- P4: gate + vector update (no internal barriers) ----
    {
        float4 g0 = make_float4(0,0,0,0), g1 = g0;
        do_gemm(sH, LDA, sW, g0, g1);
        g0.x=sigmoid_f(g0.x); g0.y=sigmoid_f(g0.y); g0.z=sigmoid_f(g0.z); g0.w=sigmoid_f(g0.w);
        g1.x=sigmoid_f(g1.x); g1.y=sigmoid_f(g1.y); g1.z=sigmoid_f(g1.z); g1.w=sigmoid_f(g1.w);
        float4 wd4 = *(const float4*)&wd_l[gj*4];
        int g0i = a0+gi, g1i = a0+gi+16;
        #pragma unroll
        for (int p = 0; p < 3; ++p) {
            float4 t0 = make_float4(0,0,0,0), t1 = t0;
            if (l > 0) do_gemm(sVA[p], LDA, sM, t0, t1);
            float sp0 = sDS[gi*24 + p*8 + (gj>>1)];
            float sp1 = sDS[(gi+16)*24 + p*8 + (gj>>1)];
            if (g0i < NN) {
                float4 vi = make_float4(0,0,0,0);
                if (l > 0) vi = *(const float4*)(vin + (size_t)p*N64 + (size_t)g0i*64 + gj*4);
                float4 o;
                o.x = (vi.x + t0.x + wd4.x*sp0)*g0.x;
                o.y = (vi.y + t0.y + wd4.y*sp0)*g0.y;
                o.z = (vi.z + t0.z + wd4.z*sp0)*g0.z;
                o.w = (vi.w + t0.w + wd4.w*sp0)*g0.w;
                *(float4*)(vout + (size_t)p*N64 + (size_t)g0i*64 + gj*4) = o;
            }
            if (g1i < NN) {
                float4 vi = make_float4(0,0,0,0);
                if (l > 0) vi = *(const float4*)(vin + (size_t)p*N64 + (size_t)g1i*64 + gj*4);
                float4 o;
                o.x = (vi.x + t1.x + wd4.x*sp1)*g1.x;
                o.y = (vi.y + t1.y + wd4.y*sp1)*g1.y;
                o.z = (vi.z + t1.z + wd4.z*sp1)*g1.z;
                o.w = (vi.w + t1.w + wd4.w*sp1)*g1.w;
                *(float4*)(vout + (size_t)p*N64 + (size_t)g1i*64 + gj*4) = o;
            }
        }
    }
    __syncthreads();   // B4: done reading sW(Wg), sM(Wc), sVA, sDS (sH still live for P5)

    // ---- P5: FFN, both halves staged at once; mids in sVA[0]/sVA[1] ----
    stageW1h(W1_l, 0, sW);
    stageW1h(W1_l, 1, sM);
    __syncthreads();   // B5: W1 halves visible
    float4 u0a, u1a, u0b, u1b;
    {
        float4 c0 = make_float4(0,0,0,0), c1 = c0;
        do_gemm(sH, LDA, sW, c0, c1);
        u0a.x=gelu_f(c0.x); u0a.y=gelu_f(c0.y); u0a.z=gelu_f(c0.z); u0a.w=gelu_f(c0.w);
        u1a.x=gelu_f(c1.x); u1a.y=gelu_f(c1.y); u1a.z=gelu_f(c1.z); u1a.w=gelu_f(c1.w);
    }
    {
        float4 c0 = make_float4(0,0,0,0), c1 = c0;
        do_gemm(sH, LDA, sM, c0, c1);
        u0b.x=gelu_f(c0.x); u0b.y=gelu_f(c0.y); u0b.z=gelu_f(c0.z); u0b.w=gelu_f(c0.w);
        u1b.x=gelu_f(c1.x); u1b.y=gelu_f(c1.y); u1b.z=gelu_f(c1.z); u1b.w=gelu_f(c1.w);
    }
    // mids -> sVA planes (sVA free after B4; writes race nothing: sW/sM only read)
    *(float4*)(sVA[0] + gi*LDA + gj*4)      = u0a;
    *(float4*)(sVA[0] + (gi+16)*LDA + gj*4) = u1a;
    *(float4*)(sVA[1] + gi*LDA + gj*4)      = u0b;
    *(float4*)(sVA[1] + (gi+16)*LDA + gj*4) = u1b;
    __syncthreads();   // B6: mids visible; done reading sW/sM(W1)
    stageW(W2_l, sW);
    stageW(W2_l + 4096, sM);
    __syncthreads();   // B7: W2 halves visible
    {
        float4 c0 = *(float4*)(sS + gi*LDA + gj*4);
        float4 c1 = *(float4*)(sS + (gi+16)*LDA + gj*4);
        do_gemm(sVA[0], LDA, sW, c0, c1);
        do_gemm(sVA[1], LDA, sM, c0, c1);
        *(float4*)(sS + gi*LDA + gj*4)      = c0;
        *(float4*)(sS + (gi+16)*LDA + gj*4) = c1;
    }
    __syncthreads();   // B8: sS stable; done reading sW/sM(W2), sVA(mids)

    // ---- P6: next-layer q/k/vf (single staged phase) or pooling ----
    if (l < LAYERS-1) {
        do_ln(sS, sH);
        stageW(Wk + (l+1)*4096, sW);
        stageW(Wv + (l+1)*4096, sM);
        stageW(Wq + (l+1)*4096, (float*)sVA);
        __syncthreads();   // B9: sH + Wk/Wv/Wq visible
        { float4 c0 = make_float4(0,0,0,0), c1 = c0; do_gemm(sH, LDA, sW, c0, c1); store_g(kout, c0, c1); }
        { float4 c0 = make_float4(0,0,0,0), c1 = c0; do_gemm(sH, LDA, sM, c0, c1); store_g(vfout, c0, c1); }
        { float4 c0 = make_float4(0,0,0,0), c1 = c0; do_gemm(sH, LDA, (const float*)sVA, c0, c1); store_g(qout, c0, c1); }
        {
            int ga = a0 + lrow;
            if (ga < NN) {
                float4* dp = (float4*)(sg + (size_t)ga*64);
                const float4* sp = (const float4*)(sS + lrow*LDA);
                dp[lsub*2] = sp[lsub*2]; dp[lsub*2+1] = sp[lsub*2+1];
            }
        }
    } else {
        int ga = a0 + lrow;
        if (ga < NN) {
            int r = ridx[n2o[ga]];
            #pragma unroll
            for (int e = 0; e < 8; ++e)
                atomicAdd(&resb[r*64 + lsub*8 + e], sS[lrow*LDA + lsub*8 + e]);
        }
    }
}

// ---------------- head ----------------
__global__ void head_kernel(const float* __restrict__ res, const float* __restrict__ Wout,
                            const float* __restrict__ bout, float* __restrict__ out, int r_total) {
    int wave = threadIdx.x >> 6, lane = threadIdx.x & 63;
    int r = blockIdx.x*4 + wave;
    if (r >= r_total) return;
    float p = res[r*HID + lane] * (1.0f/APR);
    float o0 = p * Wout[lane*2 + 0];
    float o1 = p * Wout[lane*2 + 1];
    #pragma unroll
    for (int off = 1; off < 64; off <<= 1) { o0 += __shfl_xor(o0, off); o1 += __shfl_xor(o1, off); }
    if (lane == 0) { out[r*2+0] = o0 + bout[0]; out[r*2+1] = o1 + bout[1]; }
}

// ---------------- launcher ----------------
extern "C" void kernel_launch(void* const* d_in, const int* in_sizes, int n_in,
                              void* d_out, int out_size, void* d_ws, size_t ws_size,
                              hipStream_t stream) {
    const float* coords    = (const float*)d_in[0];
    const int*   atom_ids  = (const int*)d_in[1];
    const int*   res_ids   = (const int*)d_in[2];
    const int*   elem_ids  = (const int*)d_in[3];
    const int*   ridx      = (const int*)d_in[4];
    const float* emb_atom  = (const float*)d_in[5];
    const float* emb_res   = (const float*)d_in[6];
    const float* emb_elem  = (const float*)d_in[7];
    const float* Win       = (const float*)d_in[8];
    const float* Wq        = (const float*)d_in[9];
    const float* Wk        = (const float*)d_in[10];
    const float* Wv        = (const float*)d_in[11];
    const float* Wvec      = (const float*)d_in[12];
    const float* wdir      = (const float*)d_in[13];
    const float* dist_bias = (const float*)d_in[14];
    const float* Wo        = (const float*)d_in[15];
    const float* W1        = (const float*)d_in[16];
    const float* W2        = (const float*)d_in[17];
    const float* Wg        = (const float*)d_in[18];
    const float* Wout      = (const float*)d_in[19];
    const float* bout      = (const float*)d_in[20];
    float* out = (float*)d_out;

    float* ws = (float*)d_ws;
    float* qA = ws + OFF_QA;  float* kA = ws + OFF_KA;  float* fA = ws + OFF_FA;
    float* qB = ws + OFF_QB;  float* kB = ws + OFF_KB;  float* fB = ws + OFF_FB;
    float* vA = ws + OFF_VA;  float* vB = ws + OFF_VB;
    float* sg = ws + OFF_S;
    float* dirn_s = ws + OFF_DIRNS;
    float4* c4  = (float4*)(ws + OFF_C4);
    float4* c4s = (float4*)(ws + OFF_C4S);
    float* resb = ws + OFF_RES;
    int* nbr_s  = (int*)(ws + OFF_NBRS);
    int* bins_s = (int*)(ws + OFF_BINSS);
    int* o2n    = (int*)(ws + OFF_O2N);
    int* n2o    = (int*)(ws + OFF_N2O);
    int* cellid = (int*)(ws + OFF_CELL);
    int* hist   = (int*)(ws + OFF_HIST);
    int* cnt    = (int*)(ws + OFF_CNT);
    int* baseb  = (int*)(ws + OFF_BASE);

    hipMemsetAsync(hist, 0, 2*4096*sizeof(int), stream);

    pad_cell_kernel<<<(NN+255)/256, 256, 0, stream>>>(coords, c4, cellid, hist, resb, NN);
    scan_kernel<<<1, 256, 0, stream>>>(hist, baseb);
    scatter_kernel<<<(NN+255)/256, 256, 0, stream>>>(cellid, baseb, cnt, o2n, n2o, c4, c4s, NN);
    knn_grid_kernel<<<(NN+3)/4, 256, 0, stream>>>(c4s, baseb, hist, n2o, o2n, nbr_s, bins_s, dirn_s, NN);

    prologue_kernel<<<NBLK, 256, 0, stream>>>(atom_ids, res_ids, elem_ids, n2o,
                                              emb_atom, emb_res, emb_elem,
                                              Win, Wq, Wk, Wv, sg, qA, kA, fA);
    for (int l = 0; l < LAYERS; ++l) {
        int p = l & 1;
        const float* qin = p ? qB : qA;  float* qout = p ? qA : qB;
        const float* kin = p ? kB : kA;  float* kout = p ? kA : kB;
        const float* fin = p ? fB : fA;  float* fout = p ? fA : fB;
        const float* vin = p ? vB : vA;  float* vout = p ? vA : vB;
        layer_kernel<<<NBLK, 256, 0, stream>>>(qin, kin, fin, qout, kout, fout,
                                               vin, vout, sg, dirn_s, nbr_s, bins_s,
                                               resb, ridx, n2o,
                                               Wvec, wdir, dist_bias,
                                               Wo, W1, W2, Wg, Wq, Wk, Wv, l);
    }
    head_kernel<<<(RR+3)/4, 256, 0, stream>>>(resb, Wout, bout, out, RR);
}